// Round 1
// baseline (297.291 us; speedup 1.0000x reference)
//
#include <hip/hip_runtime.h>

#define B 8
#define T 512
#define TEMP_IN 32
#define STAT_IN 16
#define TEMP_H 64
#define STAT_H 32
#define ATTN_H 32
#define N_CLS 2
#define BN_INV 0.99999500003749969f
#define R 8   // query rows per attention block

// ---------------- x_s chain: x_s0 = mlp(x_stat); x_s1 = mlp(x_s0, lw_s[0]); x_s2 = mlp(x_s1, lw_s[1])
__global__ void k_prep(const float* __restrict__ x_stat,
                       const float* __restrict__ sw, const float* __restrict__ sb,
                       const float* __restrict__ sg, const float* __restrict__ sbeta,
                       const float* __restrict__ lw_s, const float* __restrict__ lb_s,
                       const float* __restrict__ lg_s, const float* __restrict__ lbeta_s,
                       float* __restrict__ xs_out /* 3 * B * STAT_H */) {
    __shared__ float cur[B][STAT_H];
    int tid = threadIdx.x;           // 256 = B*STAT_H
    int b = tid >> 5, c = tid & 31;
    float acc = sb[c];
    for (int k = 0; k < STAT_IN; ++k) acc += x_stat[b * STAT_IN + k] * sw[k * STAT_H + c];
    acc = acc * (sg[c] * BN_INV) + sbeta[c];
    acc = (acc >= 0.f) ? acc : 0.01f * acc;
    xs_out[b * STAT_H + c] = acc;
    cur[b][c] = acc;
    __syncthreads();
    for (int l = 0; l < 2; ++l) {
        float a2 = lb_s[l * STAT_H + c];
        for (int k = 0; k < STAT_H; ++k) a2 += cur[b][k] * lw_s[(l * STAT_H + k) * STAT_H + c];
        a2 = a2 * (lg_s[l * STAT_H + c] * BN_INV) + lbeta_s[l * STAT_H + c];
        a2 = (a2 >= 0.f) ? a2 : 0.01f * a2;
        __syncthreads();
        cur[b][c] = a2;
        xs_out[(l + 1) * (B * STAT_H) + b * STAT_H + c] = a2;
        __syncthreads();
    }
}

// ---------------- temp_attn: one block per (b,i) row, 256 threads, 2 j each
__global__ void k_tempattn(const float* __restrict__ t, const int* __restrict__ lengths,
                           const float* __restrict__ aw0, const float* __restrict__ ab0,
                           const float* __restrict__ ag, const float* __restrict__ abeta,
                           const float* __restrict__ aw1, const float* __restrict__ ab1,
                           float* __restrict__ temp_attn) {
    int row = blockIdx.x;
    int b = row >> 9, i = row & (T - 1);
    int tid = threadIdx.x;
    __shared__ float sh_a[T];
    __shared__ float s_w[5 * ATTN_H];
    __shared__ float redm[4], reds[4];
    if (tid < ATTN_H) {
        s_w[tid]              = aw0[tid];
        s_w[ATTN_H + tid]     = ab0[tid];
        s_w[2 * ATTN_H + tid] = ag[tid] * BN_INV;
        s_w[3 * ATTN_H + tid] = abeta[tid];
        s_w[4 * ATTN_H + tid] = aw1[tid];
    }
    // global dt max: t sorted ascending per row -> max_b(t[b,T-1]-t[b,0])
    float dtmax = 0.f;
    for (int bb = 0; bb < B; ++bb) {
        float d = t[bb * T + (T - 1)] - t[bb * T];
        dtmax = fmaxf(dtmax, d);
    }
    float inv = 1.0f / (dtmax + 1e-8f);
    __syncthreads();
    float ti = t[b * T + i];
    int len = lengths[b];
    float ab1v = ab1[0];
    for (int j = tid; j < T; j += 256) {
        float dt = (t[b * T + j] - ti) * inv;
        float a = ab1v;
        #pragma unroll
        for (int k = 0; k < ATTN_H; ++k) {
            float h = dt * s_w[k] + s_w[ATTN_H + k];
            h = h * s_w[2 * ATTN_H + k] + s_w[3 * ATTN_H + k];
            h = (h >= 0.f) ? h : 0.01f * h;
            a += h * s_w[4 * ATTN_H + k];
        }
        sh_a[j] = (j < len) ? a : -9e8f;
    }
    __syncthreads();
    float v0 = sh_a[tid], v1 = sh_a[tid + 256];
    float m = fmaxf(v0, v1);
    for (int o = 32; o > 0; o >>= 1) m = fmaxf(m, __shfl_xor(m, o));
    if ((tid & 63) == 0) redm[tid >> 6] = m;
    __syncthreads();
    m = fmaxf(fmaxf(redm[0], redm[1]), fmaxf(redm[2], redm[3]));
    float e0 = expf(v0 - m), e1 = expf(v1 - m);
    float s = e0 + e1;
    for (int o = 32; o > 0; o >>= 1) s += __shfl_xor(s, o);
    if ((tid & 63) == 0) reds[tid >> 6] = s;
    __syncthreads();
    s = reds[0] + reds[1] + reds[2] + reds[3];
    float invs = 1.0f / s;
    temp_attn[(size_t)row * T + tid] = e0 * invs;
    temp_attn[(size_t)row * T + tid + 256] = e1 * invs;
}

// ---------------- x_t init: (B*T,32)@(32,64) mlp
__global__ void k_xt0(const float* __restrict__ x_temp,
                      const float* __restrict__ tw, const float* __restrict__ tb,
                      const float* __restrict__ tg, const float* __restrict__ tbeta,
                      float* __restrict__ xt) {
    int row = blockIdx.x;
    int c = threadIdx.x;   // 64
    __shared__ float xr[TEMP_IN];
    if (c < TEMP_IN) xr[c] = x_temp[row * TEMP_IN + c];
    __syncthreads();
    float acc = tb[c];
    #pragma unroll
    for (int k = 0; k < TEMP_IN; ++k) acc += xr[k] * tw[k * TEMP_H + c];
    acc = acc * (tg[c] * BN_INV) + tbeta[c];
    xt[row * TEMP_H + c] = (acc >= 0.f) ? acc : 0.01f * acc;
}

// ---------------- layer mlp: concat(x_t[row], x_s[b]) @ lw (96x64), masked output
__global__ void k_mlp96(const float* __restrict__ xt, const float* __restrict__ xs,
                        const float* __restrict__ lw, const float* __restrict__ lb,
                        const float* __restrict__ lg, const float* __restrict__ lbeta,
                        const int* __restrict__ lengths, float* __restrict__ xout) {
    int row = blockIdx.x;
    int b = row >> 9, i = row & (T - 1);
    int c = threadIdx.x;   // 64
    __shared__ float xr[TEMP_H + STAT_H];
    xr[c] = xt[row * TEMP_H + c];
    if (c < STAT_H) xr[TEMP_H + c] = xs[b * STAT_H + c];
    __syncthreads();
    float acc = lb[c];
    #pragma unroll
    for (int k = 0; k < TEMP_H + STAT_H; ++k) acc += xr[k] * lw[k * TEMP_H + c];
    acc = acc * (lg[c] * BN_INV) + lbeta[c];
    acc = (acc >= 0.f) ? acc : 0.01f * acc;
    xout[row * TEMP_H + c] = (i < lengths[b]) ? acc : 0.f;
}

// ---------------- attention: qk = x@x^T/8, softmax (unmasked), +temp_attn, mask_j, @x, mask_i
__global__ void k_attn(const float* __restrict__ x, const float* __restrict__ temp_attn,
                       const int* __restrict__ lengths, float* __restrict__ xt_out) {
    int blk = blockIdx.x;
    int b = blk >> 6, i0 = (blk & 63) * R;
    int tid = threadIdx.x;  // 256
    __shared__ float xi[R][TEMP_H];
    __shared__ float att[R][T];
    __shared__ float part[4][R][TEMP_H];
    for (int idx = tid; idx < R * TEMP_H; idx += 256)
        xi[idx >> 6][idx & 63] = x[((size_t)(b * T + i0 + (idx >> 6))) * TEMP_H + (idx & 63)];
    __syncthreads();
    int len = lengths[b];
    // phase 1: qk rows
    for (int j = tid; j < T; j += 256) {
        const float4* xj4 = reinterpret_cast<const float4*>(&x[((size_t)(b * T + j)) * TEMP_H]);
        float acc[R];
        #pragma unroll
        for (int r = 0; r < R; ++r) acc[r] = 0.f;
        #pragma unroll
        for (int c4 = 0; c4 < TEMP_H / 4; ++c4) {
            float4 xv = xj4[c4];
            #pragma unroll
            for (int r = 0; r < R; ++r) {
                acc[r] += xi[r][c4 * 4 + 0] * xv.x;
                acc[r] += xi[r][c4 * 4 + 1] * xv.y;
                acc[r] += xi[r][c4 * 4 + 2] * xv.z;
                acc[r] += xi[r][c4 * 4 + 3] * xv.w;
            }
        }
        #pragma unroll
        for (int r = 0; r < R; ++r) att[r][j] = acc[r] * 0.125f;
    }
    __syncthreads();
    // softmax per row (raw qk, NO mask in softmax), then + temp_attn, * mask_j
    int wave = tid >> 6, lane = tid & 63;
    for (int rr = 0; rr < R / 4; ++rr) {
        int r = wave + rr * 4;
        float v[T / 64];
        float m = -1e30f;
        #pragma unroll
        for (int q = 0; q < T / 64; ++q) { v[q] = att[r][lane + q * 64]; m = fmaxf(m, v[q]); }
        for (int o = 32; o > 0; o >>= 1) m = fmaxf(m, __shfl_xor(m, o));
        float s = 0.f;
        #pragma unroll
        for (int q = 0; q < T / 64; ++q) { v[q] = expf(v[q] - m); s += v[q]; }
        for (int o = 32; o > 0; o >>= 1) s += __shfl_xor(s, o);
        float invs = 1.0f / s;
        size_t gi = ((size_t)(b * T + i0 + r)) * T;
        #pragma unroll
        for (int q = 0; q < T / 64; ++q) {
            int j = lane + q * 64;
            float a = v[q] * invs + temp_attn[gi + j];
            att[r][j] = (j < len) ? a : 0.f;
        }
    }
    __syncthreads();
    // phase 2: PV
    int c = tid & 63, chunk = tid >> 6;
    float acc[R];
    #pragma unroll
    for (int r = 0; r < R; ++r) acc[r] = 0.f;
    for (int j = chunk * (T / 4); j < (chunk + 1) * (T / 4); ++j) {
        float xv = x[((size_t)(b * T + j)) * TEMP_H + c];
        #pragma unroll
        for (int r = 0; r < R; ++r) acc[r] += att[r][j] * xv;
    }
    #pragma unroll
    for (int r = 0; r < R; ++r) part[chunk][r][c] = acc[r];
    __syncthreads();
    for (int idx = tid; idx < R * TEMP_H; idx += 256) {
        int r = idx >> 6, cc = idx & 63;
        float sum = part[0][r][cc] + part[1][r][cc] + part[2][r][cc] + part[3][r][cc];
        xt_out[((size_t)(b * T + i0 + r)) * TEMP_H + cc] = ((i0 + r) < len) ? sum : 0.f;
    }
}

// ---------------- epilogue: classifier + masked argmax(o1-o0) with lowest-index tie-break
__global__ void k_out(const float* __restrict__ xt, const float* __restrict__ xs2,
                      const float* __restrict__ cw, const float* __restrict__ cb,
                      const int* __restrict__ lengths,
                      float* __restrict__ out, float* __restrict__ outmax) {
    int b = blockIdx.x;
    int tid = threadIdx.x;  // 256
    __shared__ float s_cw[(TEMP_H + STAT_H) * N_CLS];
    __shared__ float s_xs[STAT_H];
    __shared__ float rb[4], r0[4], r1[4];
    __shared__ int ri[4];
    if (tid < (TEMP_H + STAT_H) * N_CLS) s_cw[tid] = cw[tid];
    if (tid < STAT_H) s_xs[tid] = xs2[b * STAT_H + tid];
    __syncthreads();
    int len = lengths[b];
    float cb0 = cb[0], cb1 = cb[1];
    float best = -3e30f, bv0 = 0.f, bv1 = 0.f;
    int besti = 0x7fffffff;
    for (int i = tid; i < T; i += 256) {
        const float* xr = &xt[((size_t)(b * T + i)) * TEMP_H];
        float o0 = cb0, o1 = cb1;
        #pragma unroll
        for (int k = 0; k < TEMP_H; ++k) { float v = xr[k]; o0 += v * s_cw[k * 2]; o1 += v * s_cw[k * 2 + 1]; }
        #pragma unroll
        for (int k = 0; k < STAT_H; ++k) { float v = s_xs[k]; o0 += v * s_cw[(TEMP_H + k) * 2]; o1 += v * s_cw[(TEMP_H + k) * 2 + 1]; }
        bool valid = i < len;
        if (!valid) { o0 = 0.f; o1 = 0.f; }
        out[((size_t)(b * T + i)) * N_CLS] = o0;
        out[((size_t)(b * T + i)) * N_CLS + 1] = o1;
        float diff = valid ? (o1 - o0) : -1e30f;
        if (diff > best || (diff == best && i < besti)) { best = diff; bv0 = o0; bv1 = o1; besti = i; }
    }
    for (int o = 32; o > 0; o >>= 1) {
        float ob = __shfl_xor(best, o), o0s = __shfl_xor(bv0, o), o1s = __shfl_xor(bv1, o);
        int oi = __shfl_xor(besti, o);
        if (ob > best || (ob == best && oi < besti)) { best = ob; bv0 = o0s; bv1 = o1s; besti = oi; }
    }
    if ((tid & 63) == 0) { rb[tid >> 6] = best; r0[tid >> 6] = bv0; r1[tid >> 6] = bv1; ri[tid >> 6] = besti; }
    __syncthreads();
    if (tid == 0) {
        for (int w = 1; w < 4; ++w) {
            if (rb[w] > best || (rb[w] == best && ri[w] < besti)) { best = rb[w]; bv0 = r0[w]; bv1 = r1[w]; besti = ri[w]; }
        }
        outmax[b * 2] = bv0;
        outmax[b * 2 + 1] = bv1;
    }
}

extern "C" void kernel_launch(void* const* d_in, const int* in_sizes, int n_in,
                              void* d_out, int out_size, void* d_ws, size_t ws_size,
                              hipStream_t stream) {
    const float* x_temp  = (const float*)d_in[0];
    const float* x_stat  = (const float*)d_in[1];
    const float* t       = (const float*)d_in[2];
    const int*   lengths = (const int*)d_in[4];
    const float* aw0 = (const float*)d_in[5];
    const float* ab0 = (const float*)d_in[6];
    const float* ag  = (const float*)d_in[7];
    const float* abeta = (const float*)d_in[8];
    const float* aw1 = (const float*)d_in[9];
    const float* ab1 = (const float*)d_in[10];
    const float* tw  = (const float*)d_in[11];
    const float* tb  = (const float*)d_in[12];
    const float* tg  = (const float*)d_in[13];
    const float* tbeta = (const float*)d_in[14];
    const float* sw  = (const float*)d_in[15];
    const float* sb  = (const float*)d_in[16];
    const float* sg  = (const float*)d_in[17];
    const float* sbeta = (const float*)d_in[18];
    const float* lw_t = (const float*)d_in[19];
    const float* lb_t = (const float*)d_in[20];
    const float* lg_t = (const float*)d_in[21];
    const float* lbeta_t = (const float*)d_in[22];
    const float* lw_s = (const float*)d_in[23];
    const float* lb_s = (const float*)d_in[24];
    const float* lg_s = (const float*)d_in[25];
    const float* lbeta_s = (const float*)d_in[26];
    const float* cw = (const float*)d_in[27];
    const float* cb = (const float*)d_in[28];

    float* ws = (float*)d_ws;
    float* temp_attn = ws;                                   // B*T*T
    float* XT = ws + (size_t)B * T * T;                      // B*T*64
    float* XL = XT + (size_t)B * T * TEMP_H;                 // B*T*64
    float* XS = XL + (size_t)B * T * TEMP_H;                 // 3*B*32
    float* out = (float*)d_out;
    float* outmax = out + (size_t)B * T * N_CLS;

    k_prep<<<1, 256, 0, stream>>>(x_stat, sw, sb, sg, sbeta, lw_s, lb_s, lg_s, lbeta_s, XS);
    k_tempattn<<<B * T, 256, 0, stream>>>(t, lengths, aw0, ab0, ag, abeta, aw1, ab1, temp_attn);
    k_xt0<<<B * T, 64, 0, stream>>>(x_temp, tw, tb, tg, tbeta, XT);
    for (int l = 0; l < 2; ++l) {
        k_mlp96<<<B * T, 64, 0, stream>>>(XT, XS + l * B * STAT_H,
                                          lw_t + (size_t)l * (TEMP_H + STAT_H) * TEMP_H,
                                          lb_t + l * TEMP_H, lg_t + l * TEMP_H, lbeta_t + l * TEMP_H,
                                          lengths, XL);
        k_attn<<<B * (T / R), 256, 0, stream>>>(XL, temp_attn, lengths, XT);
    }
    k_out<<<B, 256, 0, stream>>>(XT, XS + 2 * B * STAT_H, cw, cb, lengths, out, outmax);
}

// Round 2
// 286.903 us; speedup vs baseline: 1.0362x; 1.0362x over previous
//
#include <hip/hip_runtime.h>

#define B 8
#define T 512
#define TEMP_IN 32
#define STAT_IN 16
#define TEMP_H 64
#define STAT_H 32
#define ATTN_H 32
#define N_CLS 2
#define BN_INV 0.99999500003749969f
#define R 8   // query rows per attention block

// ---------------- temp_attn (wave-per-row, register resident) + x_s chain folded into block 0
__global__ void k_temp(const float* __restrict__ t, const int* __restrict__ lengths,
                       const float* __restrict__ aw0, const float* __restrict__ ab0,
                       const float* __restrict__ ag, const float* __restrict__ abeta,
                       const float* __restrict__ aw1, const float* __restrict__ ab1,
                       const float* __restrict__ x_stat,
                       const float* __restrict__ sw, const float* __restrict__ sb,
                       const float* __restrict__ sg, const float* __restrict__ sbeta,
                       const float* __restrict__ lw_s, const float* __restrict__ lb_s,
                       const float* __restrict__ lg_s, const float* __restrict__ lbeta_s,
                       float* __restrict__ xs_out,
                       float* __restrict__ temp_attn) {
    int tid = threadIdx.x;            // 256
    int lane = tid & 63, wave = tid >> 6;
    __shared__ float s_w[5 * ATTN_H + 1];
    __shared__ float s_cur[B][STAT_H];
    if (tid < ATTN_H) {
        s_w[tid]              = aw0[tid];
        s_w[ATTN_H + tid]     = ab0[tid];
        s_w[2 * ATTN_H + tid] = ag[tid] * BN_INV;
        s_w[3 * ATTN_H + tid] = abeta[tid];
        s_w[4 * ATTN_H + tid] = aw1[tid];
    }
    if (tid == 0) s_w[5 * ATTN_H] = ab1[0];

    if (blockIdx.x == 0) {
        // x_s chain: xs0 = mlp(x_stat); xs1 = mlp(xs0); xs2 = mlp(xs1)
        int b = tid >> 5, c = tid & 31;
        float acc = sb[c];
        for (int k = 0; k < STAT_IN; ++k) acc += x_stat[b * STAT_IN + k] * sw[k * STAT_H + c];
        acc = acc * (sg[c] * BN_INV) + sbeta[c];
        acc = (acc >= 0.f) ? acc : 0.01f * acc;
        xs_out[b * STAT_H + c] = acc;
        s_cur[b][c] = acc;
        __syncthreads();
        for (int l = 0; l < 2; ++l) {
            float a2 = lb_s[l * STAT_H + c];
            for (int k = 0; k < STAT_H; ++k) a2 += s_cur[b][k] * lw_s[(l * STAT_H + k) * STAT_H + c];
            a2 = a2 * (lg_s[l * STAT_H + c] * BN_INV) + lbeta_s[l * STAT_H + c];
            a2 = (a2 >= 0.f) ? a2 : 0.01f * a2;
            __syncthreads();
            s_cur[b][c] = a2;
            xs_out[(l + 1) * (B * STAT_H) + b * STAT_H + c] = a2;
            __syncthreads();
        }
    }
    __syncthreads();

    // one wave per query row
    int row = blockIdx.x * 4 + wave;
    int b = row >> 9, i = row & (T - 1);
    float dtmax = 0.f;
    #pragma unroll
    for (int bb = 0; bb < B; ++bb) {
        float d = t[bb * T + (T - 1)] - t[bb * T];
        dtmax = fmaxf(dtmax, d);
    }
    float inv = 1.0f / (dtmax + 1e-8f);
    float ti = t[b * T + i];
    int len = lengths[b];
    float ab1v = s_w[5 * ATTN_H];

    float v[T / 64];
    float m = -1e30f;
    #pragma unroll
    for (int q = 0; q < T / 64; ++q) {
        int j = lane + q * 64;
        float dt = (t[b * T + j] - ti) * inv;
        float a = ab1v;
        #pragma unroll
        for (int k = 0; k < ATTN_H; ++k) {
            float h = dt * s_w[k] + s_w[ATTN_H + k];
            h = h * s_w[2 * ATTN_H + k] + s_w[3 * ATTN_H + k];
            h = (h >= 0.f) ? h : 0.01f * h;
            a += h * s_w[4 * ATTN_H + k];
        }
        v[q] = (j < len) ? a : -9e8f;
        m = fmaxf(m, v[q]);
    }
    for (int o = 32; o > 0; o >>= 1) m = fmaxf(m, __shfl_xor(m, o));
    float s = 0.f;
    #pragma unroll
    for (int q = 0; q < T / 64; ++q) { v[q] = expf(v[q] - m); s += v[q]; }
    for (int o = 32; o > 0; o >>= 1) s += __shfl_xor(s, o);
    float invs = 1.0f / s;
    size_t base = (size_t)row * T;
    #pragma unroll
    for (int q = 0; q < T / 64; ++q)
        __builtin_nontemporal_store(v[q] * invs, &temp_attn[base + lane + q * 64]);
}

// ---------------- fused x_t init + layer-0 mlp96 (row-local chain), 4 rows per block
__global__ void k_front(const float* __restrict__ x_temp,
                        const float* __restrict__ tw, const float* __restrict__ tb,
                        const float* __restrict__ tg, const float* __restrict__ tbeta,
                        const float* __restrict__ xs,
                        const float* __restrict__ lw, const float* __restrict__ lb,
                        const float* __restrict__ lg, const float* __restrict__ lbeta,
                        const int* __restrict__ lengths, float* __restrict__ xout) {
    int tid = threadIdx.x;     // 256
    int g = tid >> 6, c = tid & 63;
    int row = blockIdx.x * 4 + g;
    int b = row >> 9, i = row & (T - 1);
    __shared__ float xr[4][TEMP_IN];
    __shared__ float h0[4][TEMP_H + STAT_H];
    if (c < TEMP_IN) xr[g][c] = x_temp[row * TEMP_IN + c];
    __syncthreads();
    float acc = tb[c];
    #pragma unroll
    for (int k = 0; k < TEMP_IN; ++k) acc += xr[g][k] * tw[k * TEMP_H + c];
    acc = acc * (tg[c] * BN_INV) + tbeta[c];
    acc = (acc >= 0.f) ? acc : 0.01f * acc;
    h0[g][c] = acc;
    if (c < STAT_H) h0[g][TEMP_H + c] = xs[b * STAT_H + c];
    __syncthreads();
    float a2 = lb[c];
    #pragma unroll
    for (int k = 0; k < TEMP_H + STAT_H; ++k) a2 += h0[g][k] * lw[k * TEMP_H + c];
    a2 = a2 * (lg[c] * BN_INV) + lbeta[c];
    a2 = (a2 >= 0.f) ? a2 : 0.01f * a2;
    xout[(size_t)row * TEMP_H + c] = (i < lengths[b]) ? a2 : 0.f;
}

// ---------------- layer mlp: concat(x_t[row], x_s[b]) @ lw (96x64), 4 rows per block
__global__ void k_mlp96(const float* __restrict__ xt, const float* __restrict__ xs,
                        const float* __restrict__ lw, const float* __restrict__ lb,
                        const float* __restrict__ lg, const float* __restrict__ lbeta,
                        const int* __restrict__ lengths, float* __restrict__ xout) {
    int tid = threadIdx.x;     // 256
    int g = tid >> 6, c = tid & 63;
    int row = blockIdx.x * 4 + g;
    int b = row >> 9, i = row & (T - 1);
    __shared__ float h0[4][TEMP_H + STAT_H];
    h0[g][c] = xt[(size_t)row * TEMP_H + c];
    if (c < STAT_H) h0[g][TEMP_H + c] = xs[b * STAT_H + c];
    __syncthreads();
    float a2 = lb[c];
    #pragma unroll
    for (int k = 0; k < TEMP_H + STAT_H; ++k) a2 += h0[g][k] * lw[k * TEMP_H + c];
    a2 = a2 * (lg[c] * BN_INV) + lbeta[c];
    a2 = (a2 >= 0.f) ? a2 : 0.01f * a2;
    xout[(size_t)row * TEMP_H + c] = (i < lengths[b]) ? a2 : 0.f;
}

// ---------------- attention: qk = x@x^T/8, softmax (unmasked), +temp_attn, mask_j, @x, mask_i
__global__ void k_attn(const float* __restrict__ x, const float* __restrict__ temp_attn,
                       const int* __restrict__ lengths, float* __restrict__ xt_out) {
    int blk = blockIdx.x;
    int b = blk >> 6, i0 = (blk & 63) * R;
    int tid = threadIdx.x;  // 256
    __shared__ float xi[R][TEMP_H];
    __shared__ float att[R][T];
    __shared__ float part[4][R][TEMP_H];
    for (int idx = tid; idx < R * TEMP_H; idx += 256)
        xi[idx >> 6][idx & 63] = x[((size_t)(b * T + i0 + (idx >> 6))) * TEMP_H + (idx & 63)];
    __syncthreads();
    int len = lengths[b];
    // phase 1: qk rows
    for (int j = tid; j < T; j += 256) {
        const float4* xj4 = reinterpret_cast<const float4*>(&x[((size_t)(b * T + j)) * TEMP_H]);
        float acc[R];
        #pragma unroll
        for (int r = 0; r < R; ++r) acc[r] = 0.f;
        #pragma unroll
        for (int c4 = 0; c4 < TEMP_H / 4; ++c4) {
            float4 xv = xj4[c4];
            #pragma unroll
            for (int r = 0; r < R; ++r) {
                acc[r] += xi[r][c4 * 4 + 0] * xv.x;
                acc[r] += xi[r][c4 * 4 + 1] * xv.y;
                acc[r] += xi[r][c4 * 4 + 2] * xv.z;
                acc[r] += xi[r][c4 * 4 + 3] * xv.w;
            }
        }
        #pragma unroll
        for (int r = 0; r < R; ++r) att[r][j] = acc[r] * 0.125f;
    }
    __syncthreads();
    // softmax per row (raw qk, NO mask in softmax), then + temp_attn, * mask_j
    int wave = tid >> 6, lane = tid & 63;
    for (int rr = 0; rr < R / 4; ++rr) {
        int r = wave + rr * 4;
        float v[T / 64];
        float m = -1e30f;
        #pragma unroll
        for (int q = 0; q < T / 64; ++q) { v[q] = att[r][lane + q * 64]; m = fmaxf(m, v[q]); }
        for (int o = 32; o > 0; o >>= 1) m = fmaxf(m, __shfl_xor(m, o));
        float s = 0.f;
        #pragma unroll
        for (int q = 0; q < T / 64; ++q) { v[q] = expf(v[q] - m); s += v[q]; }
        for (int o = 32; o > 0; o >>= 1) s += __shfl_xor(s, o);
        float invs = 1.0f / s;
        size_t gi = ((size_t)(b * T + i0 + r)) * T;
        #pragma unroll
        for (int q = 0; q < T / 64; ++q) {
            int j = lane + q * 64;
            float a = v[q] * invs + __builtin_nontemporal_load(&temp_attn[gi + j]);
            att[r][j] = (j < len) ? a : 0.f;
        }
    }
    __syncthreads();
    // phase 2: PV
    int c = tid & 63, chunk = tid >> 6;
    float acc[R];
    #pragma unroll
    for (int r = 0; r < R; ++r) acc[r] = 0.f;
    for (int j = chunk * (T / 4); j < (chunk + 1) * (T / 4); ++j) {
        float xv = x[((size_t)(b * T + j)) * TEMP_H + c];
        #pragma unroll
        for (int r = 0; r < R; ++r) acc[r] += att[r][j] * xv;
    }
    #pragma unroll
    for (int r = 0; r < R; ++r) part[chunk][r][c] = acc[r];
    __syncthreads();
    for (int idx = tid; idx < R * TEMP_H; idx += 256) {
        int r = idx >> 6, cc = idx & 63;
        float sum = part[0][r][cc] + part[1][r][cc] + part[2][r][cc] + part[3][r][cc];
        xt_out[((size_t)(b * T + i0 + r)) * TEMP_H + cc] = ((i0 + r) < len) ? sum : 0.f;
    }
}

// ---------------- epilogue: classifier + masked argmax(o1-o0) with lowest-index tie-break
__global__ void k_out(const float* __restrict__ xt, const float* __restrict__ xs2,
                      const float* __restrict__ cw, const float* __restrict__ cb,
                      const int* __restrict__ lengths,
                      float* __restrict__ out, float* __restrict__ outmax) {
    int b = blockIdx.x;
    int tid = threadIdx.x;  // 256
    __shared__ float s_cw[(TEMP_H + STAT_H) * N_CLS];
    __shared__ float s_xs[STAT_H];
    __shared__ float rb[4], r0[4], r1[4];
    __shared__ int ri[4];
    if (tid < (TEMP_H + STAT_H) * N_CLS) s_cw[tid] = cw[tid];
    if (tid < STAT_H) s_xs[tid] = xs2[b * STAT_H + tid];
    __syncthreads();
    int len = lengths[b];
    float cb0 = cb[0], cb1 = cb[1];
    float best = -3e30f, bv0 = 0.f, bv1 = 0.f;
    int besti = 0x7fffffff;
    for (int i = tid; i < T; i += 256) {
        const float* xr = &xt[((size_t)(b * T + i)) * TEMP_H];
        float o0 = cb0, o1 = cb1;
        #pragma unroll
        for (int k = 0; k < TEMP_H; ++k) { float v = xr[k]; o0 += v * s_cw[k * 2]; o1 += v * s_cw[k * 2 + 1]; }
        #pragma unroll
        for (int k = 0; k < STAT_H; ++k) { float v = s_xs[k]; o0 += v * s_cw[(TEMP_H + k) * 2]; o1 += v * s_cw[(TEMP_H + k) * 2 + 1]; }
        bool valid = i < len;
        if (!valid) { o0 = 0.f; o1 = 0.f; }
        out[((size_t)(b * T + i)) * N_CLS] = o0;
        out[((size_t)(b * T + i)) * N_CLS + 1] = o1;
        float diff = valid ? (o1 - o0) : -1e30f;
        if (diff > best || (diff == best && i < besti)) { best = diff; bv0 = o0; bv1 = o1; besti = i; }
    }
    for (int o = 32; o > 0; o >>= 1) {
        float ob = __shfl_xor(best, o), o0s = __shfl_xor(bv0, o), o1s = __shfl_xor(bv1, o);
        int oi = __shfl_xor(besti, o);
        if (ob > best || (ob == best && oi < besti)) { best = ob; bv0 = o0s; bv1 = o1s; besti = oi; }
    }
    if ((tid & 63) == 0) { rb[tid >> 6] = best; r0[tid >> 6] = bv0; r1[tid >> 6] = bv1; ri[tid >> 6] = besti; }
    __syncthreads();
    if (tid == 0) {
        for (int w = 1; w < 4; ++w) {
            if (rb[w] > best || (rb[w] == best && ri[w] < besti)) { best = rb[w]; bv0 = r0[w]; bv1 = r1[w]; besti = ri[w]; }
        }
        outmax[b * 2] = bv0;
        outmax[b * 2 + 1] = bv1;
    }
}

extern "C" void kernel_launch(void* const* d_in, const int* in_sizes, int n_in,
                              void* d_out, int out_size, void* d_ws, size_t ws_size,
                              hipStream_t stream) {
    const float* x_temp  = (const float*)d_in[0];
    const float* x_stat  = (const float*)d_in[1];
    const float* t       = (const float*)d_in[2];
    const int*   lengths = (const int*)d_in[4];
    const float* aw0 = (const float*)d_in[5];
    const float* ab0 = (const float*)d_in[6];
    const float* ag  = (const float*)d_in[7];
    const float* abeta = (const float*)d_in[8];
    const float* aw1 = (const float*)d_in[9];
    const float* ab1 = (const float*)d_in[10];
    const float* tw  = (const float*)d_in[11];
    const float* tb  = (const float*)d_in[12];
    const float* tg  = (const float*)d_in[13];
    const float* tbeta = (const float*)d_in[14];
    const float* sw  = (const float*)d_in[15];
    const float* sb  = (const float*)d_in[16];
    const float* sg  = (const float*)d_in[17];
    const float* sbeta = (const float*)d_in[18];
    const float* lw_t = (const float*)d_in[19];
    const float* lb_t = (const float*)d_in[20];
    const float* lg_t = (const float*)d_in[21];
    const float* lbeta_t = (const float*)d_in[22];
    const float* lw_s = (const float*)d_in[23];
    const float* lb_s = (const float*)d_in[24];
    const float* lg_s = (const float*)d_in[25];
    const float* lbeta_s = (const float*)d_in[26];
    const float* cw = (const float*)d_in[27];
    const float* cb = (const float*)d_in[28];

    float* ws = (float*)d_ws;
    float* temp_attn = ws;                                   // B*T*T
    float* XT = ws + (size_t)B * T * T;                      // B*T*64
    float* XL = XT + (size_t)B * T * TEMP_H;                 // B*T*64
    float* XS = XL + (size_t)B * T * TEMP_H;                 // 3*B*32
    float* out = (float*)d_out;
    float* outmax = out + (size_t)B * T * N_CLS;

    k_temp<<<B * T / 4, 256, 0, stream>>>(t, lengths, aw0, ab0, ag, abeta, aw1, ab1,
                                          x_stat, sw, sb, sg, sbeta, lw_s, lb_s, lg_s, lbeta_s,
                                          XS, temp_attn);
    k_front<<<B * T / 4, 256, 0, stream>>>(x_temp, tw, tb, tg, tbeta, XS,
                                           lw_t, lb_t, lg_t, lbeta_t, lengths, XL);
    k_attn<<<B * (T / R), 256, 0, stream>>>(XL, temp_attn, lengths, XT);
    k_mlp96<<<B * T / 4, 256, 0, stream>>>(XT, XS + B * STAT_H,
                                           lw_t + (size_t)(TEMP_H + STAT_H) * TEMP_H,
                                           lb_t + TEMP_H, lg_t + TEMP_H, lbeta_t + TEMP_H,
                                           lengths, XL);
    k_attn<<<B * (T / R), 256, 0, stream>>>(XL, temp_attn, lengths, XT);
    k_out<<<B, 256, 0, stream>>>(XT, XS + 2 * B * STAT_H, cw, cb, lengths, out, outmax);
}